// Round 1
// baseline (2371.213 us; speedup 1.0000x reference)
//
#include <hip/hip_runtime.h>
#include <cstdint>
#include <cmath>

#define NH 16
#define HD 64
#define SQ 2048
#define NB 4
#define DM 1024

// bucket(delta) per MT5 relative_position_bucket (bidirectional, 32 buckets, max_dist 128)
__device__ __forceinline__ int rel_bucket(int delta) {
    int b = (delta > 0) ? 16 : 0;
    int a = (delta < 0) ? -delta : delta;
    if (a < 8) return b + a;
    // 8 + floor(log(a/8)/log(16)*8); margin to integer boundaries ~1.6e-2 >> __logf err
    int large = 8 + (int)(__logf((float)a * 0.125f) * 2.8853900817779268f);
    return b + (large < 15 ? large : 15);
}

// ---- GEMM: X[8192,1024] * W[1024,1024] -> out -------------------------------
// SCATTER=1: out[((b*16+h)*2048+s)*64+d] for row m=(b,s), col n=(h,d)
// SCATTER=0: out[m*1024+n] row-major
template <int SCATTER>
__global__ __launch_bounds__(256) void proj_gemm(const float* __restrict__ X,
                                                 const float* __restrict__ W,
                                                 float* __restrict__ out) {
    __shared__ float As[16][132];  // [k][m], pad 132: writes 2-way, reads 2-way, rows 16B-aligned
    __shared__ float Bs[16][64];   // [k][n]
    const int tid = threadIdx.x;
    const int tx = tid & 15;   // 16 col groups * 4 cols
    const int ty = tid >> 4;   // 16 row groups * (4 + 4 split) rows
    const int m0 = blockIdx.y * 128;
    const int n0 = blockIdx.x * 64;

    float acc[8][4];
#pragma unroll
    for (int i = 0; i < 8; ++i)
#pragma unroll
        for (int j = 0; j < 4; ++j) acc[i][j] = 0.f;

    for (int k0 = 0; k0 < DM; k0 += 16) {
#pragma unroll
        for (int i = 0; i < 8; ++i) {   // A tile 128x16
            int e = tid + i * 256;
            int r = e >> 4, c = e & 15;
            As[c][r] = X[(size_t)(m0 + r) * DM + k0 + c];
        }
#pragma unroll
        for (int i = 0; i < 4; ++i) {   // B tile 16x64
            int e = tid + i * 256;
            int r = e >> 6, c = e & 63;
            Bs[r][c] = W[(size_t)(k0 + r) * DM + n0 + c];
        }
        __syncthreads();
#pragma unroll
        for (int kk = 0; kk < 16; ++kk) {
            float4 a0 = *(const float4*)&As[kk][ty * 4];
            float4 a1 = *(const float4*)&As[kk][64 + ty * 4];
            float4 b0 = *(const float4*)&Bs[kk][tx * 4];
            float av[8] = {a0.x, a0.y, a0.z, a0.w, a1.x, a1.y, a1.z, a1.w};
            float bv[4] = {b0.x, b0.y, b0.z, b0.w};
#pragma unroll
            for (int i = 0; i < 8; ++i)
#pragma unroll
                for (int j = 0; j < 4; ++j) acc[i][j] = fmaf(av[i], bv[j], acc[i][j]);
        }
        __syncthreads();
    }

#pragma unroll
    for (int i = 0; i < 8; ++i) {
        int r = (i < 4) ? (ty * 4 + i) : (64 + ty * 4 + (i - 4));
        int m = m0 + r;
        float4 o = make_float4(acc[i][0], acc[i][1], acc[i][2], acc[i][3]);
        if (SCATTER) {
            int bb = m >> 11, s = m & 2047;
            int n = n0 + tx * 4;
            int h = n >> 6, d = n & 63;
            *(float4*)&out[((size_t)(bb * NH + h) * SQ + s) * HD + d] = o;
        } else {
            *(float4*)&out[(size_t)m * DM + n0 + tx * 4] = o;
        }
    }
}

// ---- scores: attw[b,h,i,j] = q[b,h,i,:]·k[b,h,j,:] + bias(j-i,h) ------------
__global__ __launch_bounds__(256) void qk_scores(const float* __restrict__ q,
                                                 const float* __restrict__ k,
                                                 const float* __restrict__ table,
                                                 float* __restrict__ attw) {
    __shared__ float Qs[64][68];  // [d][i]; pad 68: writes/reads 2-way free, rows 16B-aligned
    __shared__ float Ks[64][68];  // [d][j]
    __shared__ float biasL[128];
    const int tid = threadIdx.x;
    const int tx = tid & 15, ty = tid >> 4;
    const int j0 = blockIdx.x * 64, i0 = blockIdx.y * 64;
    const int bh = blockIdx.z;
    const int h = bh & 15;
    const size_t qbase = (size_t)bh * SQ * HD + (size_t)i0 * HD;
    const size_t kbase = (size_t)bh * SQ * HD + (size_t)j0 * HD;

#pragma unroll
    for (int dc = 0; dc < 4; ++dc)
#pragma unroll
        for (int i = 0; i < 4; ++i) {
            int e = tid + i * 256;
            int r = e >> 4, c = e & 15;  // r: row (i/j), c: d within chunk
            Qs[dc * 16 + c][r] = q[qbase + (size_t)r * HD + dc * 16 + c];
            Ks[dc * 16 + c][r] = k[kbase + (size_t)r * HD + dc * 16 + c];
        }
    if (tid < 127) {
        int delta = (j0 - i0) + tid - 63;
        biasL[tid] = table[rel_bucket(delta) * NH + h];
    }
    __syncthreads();

    float acc[4][4] = {};
#pragma unroll
    for (int d = 0; d < 64; ++d) {
        float4 qv = *(const float4*)&Qs[d][ty * 4];
        float4 kv = *(const float4*)&Ks[d][tx * 4];
        float av[4] = {qv.x, qv.y, qv.z, qv.w};
        float bv[4] = {kv.x, kv.y, kv.z, kv.w};
#pragma unroll
        for (int i = 0; i < 4; ++i)
#pragma unroll
            for (int j = 0; j < 4; ++j) acc[i][j] = fmaf(av[i], bv[j], acc[i][j]);
    }

#pragma unroll
    for (int m = 0; m < 4; ++m) {
        int i = i0 + ty * 4 + m;
        int bofs = 63 + tx * 4 - ty * 4 - m;  // biasL idx for n=0
        float4 o = make_float4(acc[m][0] + biasL[bofs + 0], acc[m][1] + biasL[bofs + 1],
                               acc[m][2] + biasL[bofs + 2], acc[m][3] + biasL[bofs + 3]);
        *(float4*)&attw[(size_t)bh * SQ * SQ + (size_t)i * SQ + j0 + tx * 4] = o;
    }
}

// ---- row softmax in place, one block per row --------------------------------
__global__ __launch_bounds__(256) void softmax_rows(float* __restrict__ w) {
    __shared__ float red[8];
    const int tid = threadIdx.x;
    const size_t base = (size_t)blockIdx.x * SQ;
    float4 x0 = *(const float4*)&w[base + tid * 4];
    float4 x1 = *(const float4*)&w[base + 1024 + tid * 4];
    float v[8] = {x0.x, x0.y, x0.z, x0.w, x1.x, x1.y, x1.z, x1.w};
    float m = v[0];
#pragma unroll
    for (int i = 1; i < 8; ++i) m = fmaxf(m, v[i]);
#pragma unroll
    for (int o = 32; o > 0; o >>= 1) m = fmaxf(m, __shfl_xor(m, o));
    if ((tid & 63) == 0) red[tid >> 6] = m;
    __syncthreads();
    m = fmaxf(fmaxf(red[0], red[1]), fmaxf(red[2], red[3]));
    float s = 0.f;
#pragma unroll
    for (int i = 0; i < 8; ++i) {
        v[i] = __expf(v[i] - m);
        s += v[i];
    }
#pragma unroll
    for (int o = 32; o > 0; o >>= 1) s += __shfl_xor(s, o);
    if ((tid & 63) == 0) red[4 + (tid >> 6)] = s;
    __syncthreads();
    s = (red[4] + red[5]) + (red[6] + red[7]);
    float inv = 1.0f / s;
    *(float4*)&w[base + tid * 4] = make_float4(v[0] * inv, v[1] * inv, v[2] * inv, v[3] * inv);
    *(float4*)&w[base + 1024 + tid * 4] =
        make_float4(v[4] * inv, v[5] * inv, v[6] * inv, v[7] * inv);
}

// ---- PV: ctx[b,i,h*64+d] = sum_j attw[b,h,i,j] * v[b,h,j,d] -----------------
__global__ __launch_bounds__(256) void pv_gemm(const float* __restrict__ p,
                                               const float* __restrict__ v,
                                               float* __restrict__ ctx) {
    __shared__ float Ps[64][68];  // [j][i]
    __shared__ float Vs[64][68];  // [j][d]
    const int tid = threadIdx.x;
    const int tx = tid & 15, ty = tid >> 4;
    const int i0 = blockIdx.x * 64;
    const int bh = blockIdx.y;
    const int b = bh >> 4, h = bh & 15;
    const size_t pbase = (size_t)bh * SQ * SQ + (size_t)i0 * SQ;
    const size_t vbase = (size_t)bh * SQ * HD;

    float acc[4][4] = {};
    for (int j0 = 0; j0 < SQ; j0 += 64) {
#pragma unroll
        for (int jc = 0; jc < 4; ++jc)
#pragma unroll
            for (int i = 0; i < 4; ++i) {
                int e = tid + i * 256;
                int r = e >> 4, c = e & 15;  // r: i-row, c: j within chunk
                Ps[jc * 16 + c][r] = p[pbase + (size_t)r * SQ + j0 + jc * 16 + c];
            }
#pragma unroll
        for (int i = 0; i < 16; ++i) {
            int e = tid + i * 256;
            int r = e >> 6, c = e & 63;  // r: j, c: d
            Vs[r][c] = v[vbase + (size_t)(j0 + r) * HD + c];
        }
        __syncthreads();
#pragma unroll
        for (int j = 0; j < 64; ++j) {
            float4 pv4 = *(const float4*)&Ps[j][ty * 4];
            float4 vv4 = *(const float4*)&Vs[j][tx * 4];
            float av[4] = {pv4.x, pv4.y, pv4.z, pv4.w};
            float bv[4] = {vv4.x, vv4.y, vv4.z, vv4.w};
#pragma unroll
            for (int i = 0; i < 4; ++i)
#pragma unroll
                for (int jj = 0; jj < 4; ++jj) acc[i][jj] = fmaf(av[i], bv[jj], acc[i][jj]);
        }
        __syncthreads();
    }
#pragma unroll
    for (int m = 0; m < 4; ++m) {
        size_t row = (size_t)(b * SQ + i0 + ty * 4 + m);
        *(float4*)&ctx[row * DM + h * HD + tx * 4] =
            make_float4(acc[m][0], acc[m][1], acc[m][2], acc[m][3]);
    }
}

// ---- position_bias fill: pb[h,i,j] = table[bucket(j-i), h] ------------------
__global__ __launch_bounds__(256) void bias_fill(const float* __restrict__ table,
                                                 float* __restrict__ pb) {
    __shared__ float t[512];
    const int tid = threadIdx.x;
    t[tid] = table[tid];
    t[tid + 256] = table[tid + 256];
    __syncthreads();
    const int i = blockIdx.x;
    const int h = blockIdx.y;
    const size_t base = ((size_t)h * SQ + i) * SQ;
#pragma unroll
    for (int half = 0; half < 2; ++half) {
        int j = half * 1024 + tid * 4;
        float4 o;
        o.x = t[rel_bucket(j + 0 - i) * NH + h];
        o.y = t[rel_bucket(j + 1 - i) * NH + h];
        o.z = t[rel_bucket(j + 2 - i) * NH + h];
        o.w = t[rel_bucket(j + 3 - i) * NH + h];
        *(float4*)&pb[base + j] = o;
    }
}

extern "C" void kernel_launch(void* const* d_in, const int* in_sizes, int n_in, void* d_out,
                              int out_size, void* d_ws, size_t ws_size, hipStream_t stream) {
    const float* X = (const float*)d_in[0];
    const float* Wq = (const float*)d_in[1];
    const float* Wk = (const float*)d_in[2];
    const float* Wv = (const float*)d_in[3];
    const float* Wo = (const float*)d_in[4];
    const float* tbl = (const float*)d_in[5];

    float* out = (float*)d_out;
    float* attn_out = out;                              // 8,388,608 f32
    float* pb = out + (size_t)NB * SQ * DM;             // 67,108,864 f32
    float* attw = pb + (size_t)NH * SQ * SQ;            // 268,435,456 f32

    // scratch q,k,v,ctx live inside the position_bias region (33.5M of 67.1M f32);
    // bias_fill overwrites it LAST, after everything that reads them.
    float* q = pb;
    float* kk = pb + 8388608;
    float* vv = pb + 16777216;
    float* ctx = pb + 25165824;

    dim3 blk(256);
    proj_gemm<1><<<dim3(16, 64), blk, 0, stream>>>(X, Wq, q);
    proj_gemm<1><<<dim3(16, 64), blk, 0, stream>>>(X, Wk, kk);
    proj_gemm<1><<<dim3(16, 64), blk, 0, stream>>>(X, Wv, vv);
    qk_scores<<<dim3(32, 32, 64), blk, 0, stream>>>(q, kk, tbl, attw);
    softmax_rows<<<dim3(NB * NH * SQ), blk, 0, stream>>>(attw);
    pv_gemm<<<dim3(32, 64), blk, 0, stream>>>(attw, vv, ctx);
    proj_gemm<0><<<dim3(16, 64), blk, 0, stream>>>(ctx, Wo, attn_out);
    bias_fill<<<dim3(SQ, NH), blk, 0, stream>>>(tbl, pb);
}

// Round 2
// 1022.426 us; speedup vs baseline: 2.3192x; 2.3192x over previous
//
#include <hip/hip_runtime.h>
#include <cstdint>
#include <cmath>

#define NH 16
#define HD 64
#define SQ 2048
#define NB 4
#define DM 1024

typedef _Float16 half_t;
typedef _Float16 h8 __attribute__((ext_vector_type(8)));
typedef float f4 __attribute__((ext_vector_type(4)));

// bucket(delta) per MT5 relative_position_bucket (bidirectional, 32 buckets, max_dist 128)
__device__ __forceinline__ int rel_bucket(int delta) {
    int b = (delta > 0) ? 16 : 0;
    int a = (delta < 0) ? -delta : delta;
    if (a < 8) return b + a;
    int large = 8 + (int)(__logf((float)a * 0.125f) * 2.8853900817779268f);
    return b + (large < 15 ? large : 15);
}

// ---- f32 -> f16 convert (8 elems/thread, exact-size grid) -------------------
__global__ __launch_bounds__(256) void cvt_f16(const float* __restrict__ s,
                                               half_t* __restrict__ d) {
    size_t i = ((size_t)blockIdx.x * 256 + threadIdx.x) * 8;
    float4 a = *(const float4*)&s[i];
    float4 b = *(const float4*)&s[i + 4];
    half_t t[8] = {(half_t)a.x, (half_t)a.y, (half_t)a.z, (half_t)a.w,
                   (half_t)b.x, (half_t)b.y, (half_t)b.z, (half_t)b.w};
    *(h8*)&d[i] = *(h8*)t;
}

// ---- W[1024][1024] f32 -> Wt[n][k] f16 (transpose + convert) ----------------
__global__ __launch_bounds__(256) void cvt_T(const float* __restrict__ W,
                                             half_t* __restrict__ Wt) {
    __shared__ float T[64][65];
    const int k0 = blockIdx.y * 64, n0 = blockIdx.x * 64;
    const int c = threadIdx.x & 63, rr = threadIdx.x >> 6;
    for (int r = rr; r < 64; r += 4) T[r][c] = W[(size_t)(k0 + r) * DM + n0 + c];
    __syncthreads();
    for (int r = rr; r < 64; r += 4) Wt[(size_t)(n0 + r) * DM + k0 + c] = (half_t)T[c][r];
}

// ---- v[bh][s][d] f16 -> vT[bh][d][s] f16 ------------------------------------
__global__ __launch_bounds__(256) void transpose_v(const half_t* __restrict__ v,
                                                   half_t* __restrict__ vT) {
    __shared__ half_t T[64][72];  // 144B rows: h8-aligned
    const int bh = blockIdx.y, j0 = blockIdx.x * 64;
    const size_t base = (size_t)bh * (SQ * HD);
    const int t = threadIdx.x;
    for (int e = t; e < 512; e += 256) {
        int r = e >> 3, c = e & 7;
        *(h8*)&T[r][c * 8] = *(const h8*)&v[base + (size_t)(j0 + r) * HD + c * 8];
    }
    __syncthreads();
    const int d = t & 63, jc = t >> 6;  // lane d spans all banks on reads (2-way, free)
    half_t tmp[16];
#pragma unroll
    for (int jj = 0; jj < 16; ++jj) tmp[jj] = T[jc * 16 + jj][d];
    *(h8*)&vT[base + (size_t)d * SQ + j0 + jc * 16] = *(h8*)&tmp[0];
    *(h8*)&vT[base + (size_t)d * SQ + j0 + jc * 16 + 8] = *(h8*)&tmp[8];
}

// ---- MFMA GEMM: C[8192x1024] = A(f16)[8192x1024] * Bt(f16 [n][k]) -----------
// MODE 0: f16 scatter to [bh][s][d]; MODE 1: f32 row-major out
// 128x128 tile, BK=32, 4 waves (2x2), 16 MFMA/wave/kstep.
// LDS chunk-XOR swizzle: byte = row*64 + ((chunk ^ (row&3))<<4) -> b128 reads conflict-free
template <int MODE>
__global__ __launch_bounds__(256) void mm_f16(const half_t* __restrict__ A,
                                              const half_t* __restrict__ Bt,
                                              void* __restrict__ outp) {
    __shared__ half_t Al[128 * 32];
    __shared__ half_t Bl[128 * 32];
    const int tid = threadIdx.x;
    const int lane = tid & 63, w = tid >> 6;
    const int wr = w >> 1, wc = w & 1;
    const int m0 = blockIdx.y * 128, n0 = blockIdx.x * 128;

    f4 acc[4][4];
#pragma unroll
    for (int i = 0; i < 4; ++i)
#pragma unroll
        for (int j = 0; j < 4; ++j) acc[i][j] = (f4){0.f, 0.f, 0.f, 0.f};

    const int sr = tid >> 1;           // staging row (2 chunks/thread)
    const int sc0 = (tid & 1) * 2;     // chunks sc0, sc0+1
    const int kc = lane >> 4;          // frag chunk

    for (int k0 = 0; k0 < DM; k0 += 32) {
        const half_t* ga = A + (size_t)(m0 + sr) * DM + k0 + sc0 * 8;
        h8 a0 = *(const h8*)ga;
        h8 a1 = *(const h8*)(ga + 8);
        const half_t* gb = Bt + (size_t)(n0 + sr) * DM + k0 + sc0 * 8;
        h8 b0 = *(const h8*)gb;
        h8 b1 = *(const h8*)(gb + 8);
        __syncthreads();
        *(h8*)((char*)Al + sr * 64 + ((sc0 ^ (sr & 3)) << 4)) = a0;
        *(h8*)((char*)Al + sr * 64 + (((sc0 + 1) ^ (sr & 3)) << 4)) = a1;
        *(h8*)((char*)Bl + sr * 64 + ((sc0 ^ (sr & 3)) << 4)) = b0;
        *(h8*)((char*)Bl + sr * 64 + (((sc0 + 1) ^ (sr & 3)) << 4)) = b1;
        __syncthreads();
        h8 af[4], bf[4];
#pragma unroll
        for (int ms = 0; ms < 4; ++ms) {
            int r = wr * 64 + ms * 16 + (lane & 15);
            af[ms] = *(const h8*)((const char*)Al + r * 64 + ((kc ^ (r & 3)) << 4));
        }
#pragma unroll
        for (int ns = 0; ns < 4; ++ns) {
            int r = wc * 64 + ns * 16 + (lane & 15);
            bf[ns] = *(const h8*)((const char*)Bl + r * 64 + ((kc ^ (r & 3)) << 4));
        }
#pragma unroll
        for (int ms = 0; ms < 4; ++ms)
#pragma unroll
            for (int ns = 0; ns < 4; ++ns)
                acc[ms][ns] =
                    __builtin_amdgcn_mfma_f32_16x16x32_f16(af[ms], bf[ns], acc[ms][ns], 0, 0, 0);
    }

#pragma unroll
    for (int ms = 0; ms < 4; ++ms)
#pragma unroll
        for (int ns = 0; ns < 4; ++ns)
#pragma unroll
            for (int reg = 0; reg < 4; ++reg) {
                int m = m0 + wr * 64 + ms * 16 + (lane >> 4) * 4 + reg;
                int n = n0 + wc * 64 + ns * 16 + (lane & 15);
                if (MODE == 0) {
                    int b = m >> 11, s = m & 2047, h = n >> 6, d = n & 63;
                    ((half_t*)outp)[((size_t)(b * NH + h) * SQ + s) * HD + d] =
                        (half_t)acc[ms][ns][reg];
                } else {
                    ((float*)outp)[(size_t)m * DM + n] = acc[ms][ns][reg];
                }
            }
}

// ---- fused attention: 2-pass (sum-of-exp, no-max), writes attw f32 + ctx f16
// block = (b,h) x 64-row Q tile; 4 waves each own 16 rows.
__global__ __launch_bounds__(256) void fused_attn(const half_t* __restrict__ q,
                                                  const half_t* __restrict__ k,
                                                  const half_t* __restrict__ vT,
                                                  const float* __restrict__ table,
                                                  float* __restrict__ attw,
                                                  half_t* __restrict__ ctx) {
    __shared__ float biasE[2112];    // exp(bias(delta)), idx u = j - i + i0 + 63
    __shared__ half_t P[64 * 72];    // row stride 144B (h8-aligned)
    const int tid = threadIdx.x, lane = tid & 63, w = tid >> 6;
    const int i0 = blockIdx.x * 64;
    const int bh = blockIdx.y, h = bh & 15, b = bh >> 4;
    const size_t qb = (size_t)bh * (SQ * HD);

    for (int t = tid; t < 2112; t += 256)
        biasE[t] = __expf(table[rel_bucket(t - i0 - 63) * NH + h]);

    const int qrow = i0 + w * 16 + (lane & 15);
    h8 qf0 = *(const h8*)&q[qb + (size_t)qrow * HD + (lane >> 4) * 8];
    h8 qf1 = *(const h8*)&q[qb + (size_t)qrow * HD + 32 + (lane >> 4) * 8];
    __syncthreads();

    // ---- pass 1: row sums of exp(score+bias) --------------------------------
    float srow[4] = {0.f, 0.f, 0.f, 0.f};
    for (int j0 = 0; j0 < SQ; j0 += 64) {
        f4 a[4];
#pragma unroll
        for (int ns = 0; ns < 4; ++ns) {
            const half_t* kp = &k[qb + (size_t)(j0 + ns * 16 + (lane & 15)) * HD + (lane >> 4) * 8];
            h8 kf0 = *(const h8*)kp;
            h8 kf1 = *(const h8*)(kp + 32);
            f4 z = (f4){0.f, 0.f, 0.f, 0.f};
            z = __builtin_amdgcn_mfma_f32_16x16x32_f16(qf0, kf0, z, 0, 0, 0);
            z = __builtin_amdgcn_mfma_f32_16x16x32_f16(qf1, kf1, z, 0, 0, 0);
            a[ns] = z;
        }
        const int ub = j0 + (lane & 15) + 63 - w * 16 - (lane >> 4) * 4;  // u for reg=0,ns=0
#pragma unroll
        for (int ns = 0; ns < 4; ++ns)
#pragma unroll
            for (int reg = 0; reg < 4; ++reg)
                srow[reg] += __expf(a[ns][reg]) * biasE[ub + ns * 16 - reg];
    }
#pragma unroll
    for (int reg = 0; reg < 4; ++reg) {
#pragma unroll
        for (int ofs = 1; ofs < 16; ofs <<= 1) srow[reg] += __shfl_xor(srow[reg], ofs);
        srow[reg] = 1.0f / srow[reg];
    }

    // ---- pass 2: recompute, write attw, PV ----------------------------------
    f4 o[4];
#pragma unroll
    for (int i = 0; i < 4; ++i) o[i] = (f4){0.f, 0.f, 0.f, 0.f};
    const size_t awb = (size_t)bh * ((size_t)SQ * SQ);

    for (int j0 = 0; j0 < SQ; j0 += 64) {
        f4 a[4];
#pragma unroll
        for (int ns = 0; ns < 4; ++ns) {
            const half_t* kp = &k[qb + (size_t)(j0 + ns * 16 + (lane & 15)) * HD + (lane >> 4) * 8];
            h8 kf0 = *(const h8*)kp;
            h8 kf1 = *(const h8*)(kp + 32);
            f4 z = (f4){0.f, 0.f, 0.f, 0.f};
            z = __builtin_amdgcn_mfma_f32_16x16x32_f16(qf0, kf0, z, 0, 0, 0);
            z = __builtin_amdgcn_mfma_f32_16x16x32_f16(qf1, kf1, z, 0, 0, 0);
            a[ns] = z;
        }
        __syncthreads();  // previous tile's P fully consumed
#pragma unroll
        for (int ns = 0; ns < 4; ++ns) {
            const int col = j0 + ns * 16 + (lane & 15);
#pragma unroll
            for (int reg = 0; reg < 4; ++reg) {
                const int row = w * 16 + (lane >> 4) * 4 + reg;  // 0..63 in tile
                float p = __expf(a[ns][reg]) * biasE[col + 63 - row] * srow[reg];
                attw[awb + (size_t)(i0 + row) * SQ + col] = p;
                P[row * 72 + (col - j0)] = (half_t)p;
            }
        }
        __syncthreads();
        h8 pf0 = *(const h8*)((const char*)P + (w * 16 + (lane & 15)) * 144 + (lane >> 4) * 16);
        h8 pf1 =
            *(const h8*)((const char*)P + (w * 16 + (lane & 15)) * 144 + 64 + (lane >> 4) * 16);
#pragma unroll
        for (int ns = 0; ns < 4; ++ns) {
            const half_t* vp = &vT[qb + (size_t)(ns * 16 + (lane & 15)) * SQ + j0 + (lane >> 4) * 8];
            h8 vf0 = *(const h8*)vp;
            h8 vf1 = *(const h8*)(vp + 32);
            o[ns] = __builtin_amdgcn_mfma_f32_16x16x32_f16(pf0, vf0, o[ns], 0, 0, 0);
            o[ns] = __builtin_amdgcn_mfma_f32_16x16x32_f16(pf1, vf1, o[ns], 0, 0, 0);
        }
    }
#pragma unroll
    for (int ns = 0; ns < 4; ++ns)
#pragma unroll
        for (int reg = 0; reg < 4; ++reg) {
            int row = i0 + w * 16 + (lane >> 4) * 4 + reg;
            int d = ns * 16 + (lane & 15);
            ctx[((size_t)(b * SQ + row)) * DM + h * HD + d] = (half_t)o[ns][reg];
        }
}

// ---- position_bias fill: pb[h,i,j] = table[bucket(j-i), h] ------------------
__global__ __launch_bounds__(256) void bias_fill(const float* __restrict__ table,
                                                 float* __restrict__ pb) {
    __shared__ float t[512];
    const int tid = threadIdx.x;
    t[tid] = table[tid];
    t[tid + 256] = table[tid + 256];
    __syncthreads();
    const int i = blockIdx.x;
    const int h = blockIdx.y;
    const size_t base = ((size_t)h * SQ + i) * SQ;
#pragma unroll
    for (int half = 0; half < 2; ++half) {
        int j = half * 1024 + tid * 4;
        float4 o;
        o.x = t[rel_bucket(j + 0 - i) * NH + h];
        o.y = t[rel_bucket(j + 1 - i) * NH + h];
        o.z = t[rel_bucket(j + 2 - i) * NH + h];
        o.w = t[rel_bucket(j + 3 - i) * NH + h];
        *(float4*)&pb[base + j] = o;
    }
}

extern "C" void kernel_launch(void* const* d_in, const int* in_sizes, int n_in, void* d_out,
                              int out_size, void* d_ws, size_t ws_size, hipStream_t stream) {
    const float* X = (const float*)d_in[0];
    const float* Wq = (const float*)d_in[1];
    const float* Wk = (const float*)d_in[2];
    const float* Wv = (const float*)d_in[3];
    const float* Wo = (const float*)d_in[4];
    const float* tbl = (const float*)d_in[5];

    float* out = (float*)d_out;
    float* attn_out = out;                    // 8,388,608 f32
    float* pb = out + (size_t)NB * SQ * DM;   // 67,108,864 f32
    float* attw = pb + (size_t)NH * SQ * SQ;  // 268,435,456 f32

    // f16 scratch inside pb region (109 MB of 268 MB); bias_fill overwrites LAST
    half_t* hb = (half_t*)pb;
    half_t* Xh = hb;
    half_t* qh = hb + 8388608;
    half_t* kh = hb + 16777216;
    half_t* vh = hb + 25165824;
    half_t* vTh = hb + 33554432;
    half_t* ctxh = hb + 41943040;
    half_t* Wqt = hb + 50331648;
    half_t* Wkt = hb + 51380224;
    half_t* Wvt = hb + 52428800;
    half_t* Wot = hb + 53477376;

    dim3 blk(256);
    cvt_f16<<<dim3(4096), blk, 0, stream>>>(X, Xh);
    cvt_T<<<dim3(16, 16), blk, 0, stream>>>(Wq, Wqt);
    cvt_T<<<dim3(16, 16), blk, 0, stream>>>(Wk, Wkt);
    cvt_T<<<dim3(16, 16), blk, 0, stream>>>(Wv, Wvt);
    cvt_T<<<dim3(16, 16), blk, 0, stream>>>(Wo, Wot);
    mm_f16<0><<<dim3(8, 64), blk, 0, stream>>>(Xh, Wqt, qh);
    mm_f16<0><<<dim3(8, 64), blk, 0, stream>>>(Xh, Wkt, kh);
    mm_f16<0><<<dim3(8, 64), blk, 0, stream>>>(Xh, Wvt, vh);
    transpose_v<<<dim3(32, 64), blk, 0, stream>>>(vh, vTh);
    fused_attn<<<dim3(32, 64), blk, 0, stream>>>(qh, kh, vTh, tbl, attw, ctxh);
    mm_f16<1><<<dim3(8, 64), blk, 0, stream>>>(ctxh, Wot, attn_out);
    bias_fill<<<dim3(SQ, NH), blk, 0, stream>>>(tbl, pb);
}

// Round 3
// 863.218 us; speedup vs baseline: 2.7469x; 1.1844x over previous
//
#include <hip/hip_runtime.h>
#include <cstdint>
#include <cmath>

#define NH 16
#define HD 64
#define SQ 2048
#define NB 4
#define DM 1024

typedef _Float16 half_t;
typedef _Float16 h8 __attribute__((ext_vector_type(8)));
typedef _Float16 h4 __attribute__((ext_vector_type(4)));
typedef float f4 __attribute__((ext_vector_type(4)));

// bucket(delta) per MT5 relative_position_bucket (bidirectional, 32 buckets, max_dist 128)
__device__ __forceinline__ int rel_bucket(int delta) {
    int b = (delta > 0) ? 16 : 0;
    int a = (delta < 0) ? -delta : delta;
    if (a < 8) return b + a;
    int large = 8 + (int)(__logf((float)a * 0.125f) * 2.8853900817779268f);
    return b + (large < 15 ? large : 15);
}

// async global->LDS, 16B per lane; LDS dest = wave-uniform base + lane*16
__device__ __forceinline__ void gl_lds(const half_t* g, half_t* l) {
    __builtin_amdgcn_global_load_lds((const __attribute__((address_space(1))) unsigned int*)g,
                                     (__attribute__((address_space(3))) unsigned int*)l, 16, 0, 0);
}

// ---- f32 -> f16 convert -----------------------------------------------------
__global__ __launch_bounds__(256) void cvt_f16(const float* __restrict__ s,
                                               half_t* __restrict__ d) {
    size_t i = ((size_t)blockIdx.x * 256 + threadIdx.x) * 8;
    float4 a = *(const float4*)&s[i];
    float4 b = *(const float4*)&s[i + 4];
    half_t t[8] = {(half_t)a.x, (half_t)a.y, (half_t)a.z, (half_t)a.w,
                   (half_t)b.x, (half_t)b.y, (half_t)b.z, (half_t)b.w};
    *(h8*)&d[i] = *(h8*)t;
}

// ---- W[1024][1024] f32 -> Wt[n][k] f16 (transpose + convert) ----------------
__global__ __launch_bounds__(256) void cvt_T(const float* __restrict__ W,
                                             half_t* __restrict__ Wt) {
    __shared__ float T[64][65];
    const int k0 = blockIdx.y * 64, n0 = blockIdx.x * 64;
    const int c = threadIdx.x & 63, rr = threadIdx.x >> 6;
    for (int r = rr; r < 64; r += 4) T[r][c] = W[(size_t)(k0 + r) * DM + n0 + c];
    __syncthreads();
    for (int r = rr; r < 64; r += 4) Wt[(size_t)(n0 + r) * DM + k0 + c] = (half_t)T[c][r];
}

// ---- v[bh][s][d] f16 -> vT[bh][d][s] f16 ------------------------------------
__global__ __launch_bounds__(256) void transpose_v(const half_t* __restrict__ v,
                                                   half_t* __restrict__ vT) {
    __shared__ half_t T[64][72];
    const int bh = blockIdx.y, j0 = blockIdx.x * 64;
    const size_t base = (size_t)bh * (SQ * HD);
    const int t = threadIdx.x;
    for (int e = t; e < 512; e += 256) {
        int r = e >> 3, c = e & 7;
        *(h8*)&T[r][c * 8] = *(const h8*)&v[base + (size_t)(j0 + r) * HD + c * 8];
    }
    __syncthreads();
    const int d = t & 63, jc = t >> 6;
    half_t tmp[16];
#pragma unroll
    for (int jj = 0; jj < 16; ++jj) tmp[jj] = T[jc * 16 + jj][d];
    *(h8*)&vT[base + (size_t)d * SQ + j0 + jc * 16] = *(h8*)&tmp[0];
    *(h8*)&vT[base + (size_t)d * SQ + j0 + jc * 16 + 8] = *(h8*)&tmp[8];
}

// ---- MFMA GEMM via global_load_lds (m97 structure) --------------------------
// C[8192x1024] = A(f16)[8192x1024] * Bt(f16 [n][k]); 128x128 tile, BK=32.
// LDS slot c of row r holds global chunk c ^ ((r>>1)&3)  (pre-swizzled source)
// -> ds_read_b128 frag reads span 8 distinct 16B slots over 16 lanes: 2-way, free.
template <int MODE>
__global__ __launch_bounds__(256) void mm_f16(const half_t* __restrict__ A,
                                              const half_t* __restrict__ Bt,
                                              void* __restrict__ outp) {
    __shared__ half_t Al[128 * 32];
    __shared__ half_t Bl[128 * 32];
    const int tid = threadIdx.x;
    const int lane = tid & 63, w = tid >> 6;
    const int wr = w >> 1, wc = w & 1;
    const int m0 = blockIdx.y * 128, n0 = blockIdx.x * 128;

    f4 acc[4][4];
#pragma unroll
    for (int i = 0; i < 4; ++i)
#pragma unroll
        for (int j = 0; j < 4; ++j) acc[i][j] = (f4){0.f, 0.f, 0.f, 0.f};

    const int kc = lane >> 4;
    // staging: wave w stages rows w*32..w*32+31 of A and Bt (2 instrs each)
    const int srl = lane >> 2;        // 0..15 row within 16-row group
    const int sc = lane & 3;          // LDS chunk slot

    for (int k0 = 0; k0 < DM; k0 += 32) {
#pragma unroll
        for (int inst = 0; inst < 2; ++inst) {
            int r = w * 32 + inst * 16 + srl;
            int cg = sc ^ ((r >> 1) & 3);
            gl_lds(&A[(size_t)(m0 + r) * DM + k0 + cg * 8], &Al[(w * 32 + inst * 16) * 32]);
            gl_lds(&Bt[(size_t)(n0 + r) * DM + k0 + cg * 8], &Bl[(w * 32 + inst * 16) * 32]);
        }
        __syncthreads();  // compiler emits vmcnt(0) drain here
        h8 af[4], bf[4];
#pragma unroll
        for (int ms = 0; ms < 4; ++ms) {
            int r = wr * 64 + ms * 16 + (lane & 15);
            af[ms] = *(const h8*)&Al[r * 32 + ((kc ^ ((r >> 1) & 3)) * 8)];
        }
#pragma unroll
        for (int ns = 0; ns < 4; ++ns) {
            int r = wc * 64 + ns * 16 + (lane & 15);
            bf[ns] = *(const h8*)&Bl[r * 32 + ((kc ^ ((r >> 1) & 3)) * 8)];
        }
#pragma unroll
        for (int ms = 0; ms < 4; ++ms)
#pragma unroll
            for (int ns = 0; ns < 4; ++ns)
                acc[ms][ns] =
                    __builtin_amdgcn_mfma_f32_16x16x32_f16(af[ms], bf[ns], acc[ms][ns], 0, 0, 0);
        __syncthreads();
    }

#pragma unroll
    for (int ms = 0; ms < 4; ++ms)
#pragma unroll
        for (int ns = 0; ns < 4; ++ns)
#pragma unroll
            for (int reg = 0; reg < 4; ++reg) {
                int m = m0 + wr * 64 + ms * 16 + (lane >> 4) * 4 + reg;
                int n = n0 + wc * 64 + ns * 16 + (lane & 15);
                if (MODE == 0) {
                    int b = m >> 11, s = m & 2047, h = n >> 6, d = n & 63;
                    ((half_t*)outp)[((size_t)(b * NH + h) * SQ + s) * HD + d] =
                        (half_t)acc[ms][ns][reg];
                } else {
                    ((float*)outp)[(size_t)m * DM + n] = acc[ms][ns][reg];
                }
            }
}

// ---- fused attention: swapped QK^T, 2-pass, barrier-free main loops ---------
// block = 128 q-rows of one (b,h); 4 waves x 32 rows. C-frag reg dim = j.
__global__ __launch_bounds__(256) void fused_attn(const half_t* __restrict__ q,
                                                  const half_t* __restrict__ k,
                                                  const half_t* __restrict__ vT,
                                                  const float* __restrict__ table,
                                                  float* __restrict__ attw,
                                                  half_t* __restrict__ ctx) {
    __shared__ float biasE[2176];   // exp(bias(delta)), u = j - (i - i0) + 127
    __shared__ char Psm[16384];     // per-wave 4KB: P[32 i][64 j] f16, 16B-slot XOR swizzle
    const int tid = threadIdx.x, lane = tid & 63, w = tid >> 6;

    // XCD-bijective swizzle: 1024 blocks -> xcd*128+pos; each bh (16 blocks) on one XCD
    const int id = blockIdx.x;
    const int idx = (id & 7) * 128 + (id >> 3);
    const int bh = idx >> 4, i0 = (idx & 15) * 128;
    const int h = bh & 15, b = bh >> 4;
    const size_t qb = (size_t)bh * (SQ * HD);
    const half_t* kb = k + qb;
    const half_t* vb = vT + qb;

    for (int t = tid; t < 2176; t += 256)
        biasE[t] = __expf(table[rel_bucket(t - i0 - 127) * NH + h]);

    // Q fragments (B operand): 2 i-subtiles of 16 rows per wave
    h8 qf[2][2];
#pragma unroll
    for (int isub = 0; isub < 2; ++isub) {
        const half_t* qp =
            &q[qb + (size_t)(i0 + w * 32 + isub * 16 + (lane & 15)) * HD + (lane >> 4) * 8];
        qf[isub][0] = *(const h8*)qp;
        qf[isub][1] = *(const h8*)(qp + 32);
    }
    __syncthreads();

    // ---- pass 1: row sums of exp(score)*exp(bias) ---------------------------
    float srow[2] = {0.f, 0.f};
    for (int j0 = 0; j0 < SQ; j0 += 64) {
#pragma unroll
        for (int ns = 0; ns < 4; ++ns) {
            const half_t* kp = &kb[(size_t)(j0 + ns * 16 + (lane & 15)) * HD + (lane >> 4) * 8];
            h8 kf0 = *(const h8*)kp;
            h8 kf1 = *(const h8*)(kp + 32);
#pragma unroll
            for (int isub = 0; isub < 2; ++isub) {
                f4 z = (f4){0.f, 0.f, 0.f, 0.f};
                z = __builtin_amdgcn_mfma_f32_16x16x32_f16(kf0, qf[isub][0], z, 0, 0, 0);
                z = __builtin_amdgcn_mfma_f32_16x16x32_f16(kf1, qf[isub][1], z, 0, 0, 0);
                int u0 = j0 + ns * 16 + ((lane >> 4) << 2) - (w * 32 + isub * 16 + (lane & 15)) + 127;
#pragma unroll
                for (int reg = 0; reg < 4; ++reg)
                    srow[isub] = fmaf(__expf(z[reg]), biasE[u0 + reg], srow[isub]);
            }
        }
    }
    float sinv[2];
#pragma unroll
    for (int isub = 0; isub < 2; ++isub) {
        float s = srow[isub];
        s += __shfl_xor(s, 16);
        s += __shfl_xor(s, 32);
        sinv[isub] = 1.0f / s;
    }

    // ---- pass 2: recompute, float4 attw writes, PV via per-wave LDS P -------
    f4 o[4][2];
#pragma unroll
    for (int ns = 0; ns < 4; ++ns)
#pragma unroll
        for (int isub = 0; isub < 2; ++isub) o[ns][isub] = (f4){0.f, 0.f, 0.f, 0.f};
    const size_t awb = (size_t)bh * ((size_t)SQ * SQ);
    char* Pw = Psm + w * 4096;

    for (int j0 = 0; j0 < SQ; j0 += 64) {
        f4 a[4][2];
#pragma unroll
        for (int ns = 0; ns < 4; ++ns) {
            const half_t* kp = &kb[(size_t)(j0 + ns * 16 + (lane & 15)) * HD + (lane >> 4) * 8];
            h8 kf0 = *(const h8*)kp;
            h8 kf1 = *(const h8*)(kp + 32);
#pragma unroll
            for (int isub = 0; isub < 2; ++isub) {
                f4 z = (f4){0.f, 0.f, 0.f, 0.f};
                z = __builtin_amdgcn_mfma_f32_16x16x32_f16(kf0, qf[isub][0], z, 0, 0, 0);
                z = __builtin_amdgcn_mfma_f32_16x16x32_f16(kf1, qf[isub][1], z, 0, 0, 0);
                a[ns][isub] = z;
            }
        }
#pragma unroll
        for (int ns = 0; ns < 4; ++ns)
#pragma unroll
            for (int isub = 0; isub < 2; ++isub) {
                const int wloc = w * 32 + isub * 16 + (lane & 15);
                const int jbase = ns * 16 + ((lane >> 4) << 2);
                const int u0 = j0 + jbase - wloc + 127;
                f4 p;
#pragma unroll
                for (int reg = 0; reg < 4; ++reg)
                    p[reg] = __expf(a[ns][isub][reg]) * biasE[u0 + reg] * sinv[isub];
                *(f4*)&attw[awb + (size_t)(i0 + wloc) * SQ + j0 + jbase] = p;
                // P[iloc][j] swizzled: byte = iloc*128 + ((slot ^ (iloc&7))<<4) + (jbase&4)*2
                const int iloc = isub * 16 + (lane & 15);
                h4 ph = {(half_t)p[0], (half_t)p[1], (half_t)p[2], (half_t)p[3]};
                *(h4*)&Pw[iloc * 128 + (((jbase >> 3) ^ (iloc & 7)) << 4) + ((jbase & 4) << 1)] = ph;
            }
        h8 pf[2][2];
#pragma unroll
        for (int isub = 0; isub < 2; ++isub) {
            const int iloc = isub * 16 + (lane & 15);
            pf[isub][0] = *(const h8*)&Pw[iloc * 128 + (((lane >> 4) ^ (iloc & 7)) << 4)];
            pf[isub][1] = *(const h8*)&Pw[iloc * 128 + ((((lane >> 4) + 4) ^ (iloc & 7)) << 4)];
        }
#pragma unroll
        for (int ns = 0; ns < 4; ++ns) {
            const half_t* vp = &vb[(size_t)(ns * 16 + (lane & 15)) * SQ + j0 + (lane >> 4) * 8];
            h8 vf0 = *(const h8*)vp;
            h8 vf1 = *(const h8*)(vp + 32);
#pragma unroll
            for (int isub = 0; isub < 2; ++isub) {
                o[ns][isub] =
                    __builtin_amdgcn_mfma_f32_16x16x32_f16(pf[isub][0], vf0, o[ns][isub], 0, 0, 0);
                o[ns][isub] =
                    __builtin_amdgcn_mfma_f32_16x16x32_f16(pf[isub][1], vf1, o[ns][isub], 0, 0, 0);
            }
        }
    }
#pragma unroll
    for (int ns = 0; ns < 4; ++ns)
#pragma unroll
        for (int isub = 0; isub < 2; ++isub)
#pragma unroll
            for (int reg = 0; reg < 4; ++reg) {
                int row = i0 + w * 32 + isub * 16 + (lane >> 4) * 4 + reg;
                int d = ns * 16 + (lane & 15);
                ctx[((size_t)(b * SQ + row)) * DM + h * HD + d] = (half_t)o[ns][isub][reg];
            }
}

// ---- position_bias fill: pb[h,i,j] = table[bucket(j-i), h] ------------------
__global__ __launch_bounds__(256) void bias_fill(const float* __restrict__ table,
                                                 float* __restrict__ pb) {
    __shared__ float t[512];
    const int tid = threadIdx.x;
    t[tid] = table[tid];
    t[tid + 256] = table[tid + 256];
    __syncthreads();
    const int i = blockIdx.x;
    const int h = blockIdx.y;
    const size_t base = ((size_t)h * SQ + i) * SQ;
#pragma unroll
    for (int half = 0; half < 2; ++half) {
        int j = half * 1024 + tid * 4;
        float4 o;
        o.x = t[rel_bucket(j + 0 - i) * NH + h];
        o.y = t[rel_bucket(j + 1 - i) * NH + h];
        o.z = t[rel_bucket(j + 2 - i) * NH + h];
        o.w = t[rel_bucket(j + 3 - i) * NH + h];
        *(float4*)&pb[base + j] = o;
    }
}

extern "C" void kernel_launch(void* const* d_in, const int* in_sizes, int n_in, void* d_out,
                              int out_size, void* d_ws, size_t ws_size, hipStream_t stream) {
    const float* X = (const float*)d_in[0];
    const float* Wq = (const float*)d_in[1];
    const float* Wk = (const float*)d_in[2];
    const float* Wv = (const float*)d_in[3];
    const float* Wo = (const float*)d_in[4];
    const float* tbl = (const float*)d_in[5];

    float* out = (float*)d_out;
    float* attn_out = out;                    // 8,388,608 f32
    float* pb = out + (size_t)NB * SQ * DM;   // 67,108,864 f32
    float* attw = pb + (size_t)NH * SQ * SQ;  // 268,435,456 f32

    // f16 scratch inside pb region; bias_fill overwrites LAST
    half_t* hb = (half_t*)pb;
    half_t* Xh = hb;
    half_t* qh = hb + 8388608;
    half_t* kh = hb + 16777216;
    half_t* vh = hb + 25165824;
    half_t* vTh = hb + 33554432;
    half_t* ctxh = hb + 41943040;
    half_t* Wqt = hb + 50331648;
    half_t* Wkt = hb + 51380224;
    half_t* Wvt = hb + 52428800;
    half_t* Wot = hb + 53477376;

    dim3 blk(256);
    cvt_f16<<<dim3(4096), blk, 0, stream>>>(X, Xh);
    cvt_T<<<dim3(16, 16), blk, 0, stream>>>(Wq, Wqt);
    cvt_T<<<dim3(16, 16), blk, 0, stream>>>(Wk, Wkt);
    cvt_T<<<dim3(16, 16), blk, 0, stream>>>(Wv, Wvt);
    cvt_T<<<dim3(16, 16), blk, 0, stream>>>(Wo, Wot);
    mm_f16<0><<<dim3(8, 64), blk, 0, stream>>>(Xh, Wqt, qh);
    mm_f16<0><<<dim3(8, 64), blk, 0, stream>>>(Xh, Wkt, kh);
    mm_f16<0><<<dim3(8, 64), blk, 0, stream>>>(Xh, Wvt, vh);
    transpose_v<<<dim3(32, 64), blk, 0, stream>>>(vh, vTh);
    fused_attn<<<dim3(1024), blk, 0, stream>>>(qh, kh, vTh, tbl, attw, ctxh);
    mm_f16<1><<<dim3(8, 64), blk, 0, stream>>>(ctxh, Wot, attn_out);
    bias_fill<<<dim3(SQ, NH), blk, 0, stream>>>(tbl, pb);
}

// Round 4
// 540.886 us; speedup vs baseline: 4.3839x; 1.5959x over previous
//
#include <hip/hip_runtime.h>
#include <cstdint>
#include <cmath>

#define NH 16
#define HD 64
#define SQ 2048
#define NB 4
#define DM 1024

typedef _Float16 half_t;
typedef _Float16 h8 __attribute__((ext_vector_type(8)));
typedef _Float16 h4 __attribute__((ext_vector_type(4)));
typedef float f4 __attribute__((ext_vector_type(4)));

// bucket(delta) per MT5 relative_position_bucket (bidirectional, 32 buckets, max_dist 128)
__device__ __forceinline__ int rel_bucket(int delta) {
    int b = (delta > 0) ? 16 : 0;
    int a = (delta < 0) ? -delta : delta;
    if (a < 8) return b + a;
    int large = 8 + (int)(__logf((float)a * 0.125f) * 2.8853900817779268f);
    return b + (large < 15 ? large : 15);
}

// async global->LDS, 16B per lane; LDS dest = wave-uniform base + lane*16
__device__ __forceinline__ void gl_lds(const half_t* g, half_t* l) {
    __builtin_amdgcn_global_load_lds((const __attribute__((address_space(1))) unsigned int*)g,
                                     (__attribute__((address_space(3))) unsigned int*)l, 16, 0, 0);
}

// ---- prep: X f32->f16 (blocks 0..4095) + W transposes (blocks 4096..5119) ---
__global__ __launch_bounds__(256) void prep(const float* __restrict__ X,
                                            const float* __restrict__ Wq,
                                            const float* __restrict__ Wk,
                                            const float* __restrict__ Wv,
                                            const float* __restrict__ Wo,
                                            half_t* __restrict__ Xh, half_t* __restrict__ Wqt,
                                            half_t* __restrict__ Wkt, half_t* __restrict__ Wvt,
                                            half_t* __restrict__ Wot) {
    const int id = blockIdx.x;
    if (id < 4096) {
        size_t i = ((size_t)id * 256 + threadIdx.x) * 8;
        float4 a = *(const float4*)&X[i];
        float4 b = *(const float4*)&X[i + 4];
        half_t t[8] = {(half_t)a.x, (half_t)a.y, (half_t)a.z, (half_t)a.w,
                       (half_t)b.x, (half_t)b.y, (half_t)b.z, (half_t)b.w};
        *(h8*)&Xh[i] = *(h8*)t;
        return;
    }
    __shared__ float T[64][65];
    const int t = id - 4096;
    const int which = t >> 8, tile = t & 255;
    const float* W = which == 0 ? Wq : which == 1 ? Wk : which == 2 ? Wv : Wo;
    half_t* Wt = which == 0 ? Wqt : which == 1 ? Wkt : which == 2 ? Wvt : Wot;
    const int k0 = (tile >> 4) * 64, n0 = (tile & 15) * 64;
    const int c = threadIdx.x & 63, rr = threadIdx.x >> 6;
    for (int r = rr; r < 64; r += 4) T[r][c] = W[(size_t)(k0 + r) * DM + n0 + c];
    __syncthreads();
    for (int r = rr; r < 64; r += 4) Wt[(size_t)(n0 + r) * DM + k0 + c] = (half_t)T[c][r];
}

// ---- v[bh][s][d] f16 -> vT[bh][d][s] f16 ------------------------------------
__global__ __launch_bounds__(256) void transpose_v(const half_t* __restrict__ v,
                                                   half_t* __restrict__ vT) {
    __shared__ half_t T[64][72];
    const int bh = blockIdx.y, j0 = blockIdx.x * 64;
    const size_t base = (size_t)bh * (SQ * HD);
    const int t = threadIdx.x;
    for (int e = t; e < 512; e += 256) {
        int r = e >> 3, c = e & 7;
        *(h8*)&T[r][c * 8] = *(const h8*)&v[base + (size_t)(j0 + r) * HD + c * 8];
    }
    __syncthreads();
    const int d = t & 63, jc = t >> 6;
    half_t tmp[16];
#pragma unroll
    for (int jj = 0; jj < 16; ++jj) tmp[jj] = T[jc * 16 + jj][d];
    *(h8*)&vT[base + (size_t)d * SQ + j0 + jc * 16] = *(h8*)&tmp[0];
    *(h8*)&vT[base + (size_t)d * SQ + j0 + jc * 16 + 8] = *(h8*)&tmp[8];
}

// ---- QKV MFMA GEMM: z selects W/out; 128x128 tile, BK=32, m97 structure -----
__global__ __launch_bounds__(256) void mm_qkv(const half_t* __restrict__ A,
                                              const half_t* __restrict__ Wqt,
                                              const half_t* __restrict__ Wkt,
                                              const half_t* __restrict__ Wvt,
                                              half_t* __restrict__ qo, half_t* __restrict__ ko,
                                              half_t* __restrict__ vo) {
    const int z = blockIdx.z;
    const half_t* Bt = z == 0 ? Wqt : z == 1 ? Wkt : Wvt;
    half_t* outp = z == 0 ? qo : z == 1 ? ko : vo;
    __shared__ half_t Al[128 * 32];
    __shared__ half_t Bl[128 * 32];
    const int tid = threadIdx.x;
    const int lane = tid & 63, w = tid >> 6;
    const int wr = w >> 1, wc = w & 1;
    const int m0 = blockIdx.y * 128, n0 = blockIdx.x * 128;

    f4 acc[4][4];
#pragma unroll
    for (int i = 0; i < 4; ++i)
#pragma unroll
        for (int j = 0; j < 4; ++j) acc[i][j] = (f4){0.f, 0.f, 0.f, 0.f};

    const int kc = lane >> 4;
    const int srl = lane >> 2;
    const int sc = lane & 3;

    for (int k0 = 0; k0 < DM; k0 += 32) {
#pragma unroll
        for (int inst = 0; inst < 2; ++inst) {
            int r = w * 32 + inst * 16 + srl;
            int cg = sc ^ ((r >> 1) & 3);
            gl_lds(&A[(size_t)(m0 + r) * DM + k0 + cg * 8], &Al[(w * 32 + inst * 16) * 32]);
            gl_lds(&Bt[(size_t)(n0 + r) * DM + k0 + cg * 8], &Bl[(w * 32 + inst * 16) * 32]);
        }
        __syncthreads();
        h8 af[4], bf[4];
#pragma unroll
        for (int ms = 0; ms < 4; ++ms) {
            int r = wr * 64 + ms * 16 + (lane & 15);
            af[ms] = *(const h8*)&Al[r * 32 + ((kc ^ ((r >> 1) & 3)) * 8)];
        }
#pragma unroll
        for (int ns = 0; ns < 4; ++ns) {
            int r = wc * 64 + ns * 16 + (lane & 15);
            bf[ns] = *(const h8*)&Bl[r * 32 + ((kc ^ ((r >> 1) & 3)) * 8)];
        }
#pragma unroll
        for (int ms = 0; ms < 4; ++ms)
#pragma unroll
            for (int ns = 0; ns < 4; ++ns)
                acc[ms][ns] =
                    __builtin_amdgcn_mfma_f32_16x16x32_f16(af[ms], bf[ns], acc[ms][ns], 0, 0, 0);
        __syncthreads();
    }

#pragma unroll
    for (int ms = 0; ms < 4; ++ms)
#pragma unroll
        for (int ns = 0; ns < 4; ++ns)
#pragma unroll
            for (int reg = 0; reg < 4; ++reg) {
                int m = m0 + wr * 64 + ms * 16 + (lane >> 4) * 4 + reg;
                int n = n0 + wc * 64 + ns * 16 + (lane & 15);
                int b = m >> 11, s = m & 2047, h = n >> 6, d = n & 63;
                outp[((size_t)(b * NH + h) * SQ + s) * HD + d] = (half_t)acc[ms][ns][reg];
            }
}

// ---- Wo GEMM: ctx(f16)[8192x1024] * Wot -> f32 row-major (nt stores) --------
__global__ __launch_bounds__(256) void mm_wo(const half_t* __restrict__ A,
                                             const half_t* __restrict__ Bt,
                                             float* __restrict__ outp) {
    __shared__ half_t Al[128 * 32];
    __shared__ half_t Bl[128 * 32];
    const int tid = threadIdx.x;
    const int lane = tid & 63, w = tid >> 6;
    const int wr = w >> 1, wc = w & 1;
    const int m0 = blockIdx.y * 128, n0 = blockIdx.x * 128;

    f4 acc[4][4];
#pragma unroll
    for (int i = 0; i < 4; ++i)
#pragma unroll
        for (int j = 0; j < 4; ++j) acc[i][j] = (f4){0.f, 0.f, 0.f, 0.f};

    const int kc = lane >> 4;
    const int srl = lane >> 2;
    const int sc = lane & 3;

    for (int k0 = 0; k0 < DM; k0 += 32) {
#pragma unroll
        for (int inst = 0; inst < 2; ++inst) {
            int r = w * 32 + inst * 16 + srl;
            int cg = sc ^ ((r >> 1) & 3);
            gl_lds(&A[(size_t)(m0 + r) * DM + k0 + cg * 8], &Al[(w * 32 + inst * 16) * 32]);
            gl_lds(&Bt[(size_t)(n0 + r) * DM + k0 + cg * 8], &Bl[(w * 32 + inst * 16) * 32]);
        }
        __syncthreads();
        h8 af[4], bf[4];
#pragma unroll
        for (int ms = 0; ms < 4; ++ms) {
            int r = wr * 64 + ms * 16 + (lane & 15);
            af[ms] = *(const h8*)&Al[r * 32 + ((kc ^ ((r >> 1) & 3)) * 8)];
        }
#pragma unroll
        for (int ns = 0; ns < 4; ++ns) {
            int r = wc * 64 + ns * 16 + (lane & 15);
            bf[ns] = *(const h8*)&Bl[r * 32 + ((kc ^ ((r >> 1) & 3)) * 8)];
        }
#pragma unroll
        for (int ms = 0; ms < 4; ++ms)
#pragma unroll
            for (int ns = 0; ns < 4; ++ns)
                acc[ms][ns] =
                    __builtin_amdgcn_mfma_f32_16x16x32_f16(af[ms], bf[ns], acc[ms][ns], 0, 0, 0);
        __syncthreads();
    }

#pragma unroll
    for (int ms = 0; ms < 4; ++ms)
#pragma unroll
        for (int ns = 0; ns < 4; ++ns)
#pragma unroll
            for (int reg = 0; reg < 4; ++reg) {
                int m = m0 + wr * 64 + ms * 16 + (lane >> 4) * 4 + reg;
                int n = n0 + wc * 64 + ns * 16 + (lane & 15);
                __builtin_nontemporal_store(acc[ms][ns][reg], &outp[(size_t)m * DM + n]);
            }
}

// ---- fused attention: swapped QK^T, 2-pass, LDS-staged K/V, nt attw ---------
// block = 128 q-rows of one (b,h); 4 waves x 32 rows. C-frag reg dim = j.
__global__ __launch_bounds__(256) void fused_attn(const half_t* __restrict__ q,
                                                  const half_t* __restrict__ k,
                                                  const half_t* __restrict__ vT,
                                                  const float* __restrict__ table,
                                                  float* __restrict__ attw,
                                                  half_t* __restrict__ ctx) {
    __shared__ float biasE[2176];  // exp(bias(delta)), u = j - (i - i0) + 127
    __shared__ char Psm[16384];    // per-wave 4KB: P[32 i][64 j] f16, 16B-slot XOR swizzle
    __shared__ half_t Kl[64 * 64]; // K tile: row j x 64 d; slot s of row r = chunk s^(r&7)
    __shared__ half_t Vl[64 * 64]; // V^T tile: row d x 64 j; same swizzle
    const int tid = threadIdx.x, lane = tid & 63, w = tid >> 6;

    // XCD-bijective swizzle: each bh's 16 blocks on one XCD
    const int id = blockIdx.x;
    const int idx = (id & 7) * 128 + (id >> 3);
    const int bh = idx >> 4, i0 = (idx & 15) * 128;
    const int h = bh & 15, b = bh >> 4;
    const size_t qb = (size_t)bh * (SQ * HD);
    const half_t* kb = k + qb;
    const half_t* vb = vT + qb;

    for (int t = tid; t < 2176; t += 256)
        biasE[t] = __expf(table[rel_bucket(t - i0 - 127) * NH + h]);

    h8 qf[2][2];
#pragma unroll
    for (int isub = 0; isub < 2; ++isub) {
        const half_t* qp =
            &q[qb + (size_t)(i0 + w * 32 + isub * 16 + (lane & 15)) * HD + (lane >> 4) * 8];
        qf[isub][0] = *(const h8*)qp;
        qf[isub][1] = *(const h8*)(qp + 32);
    }
    __syncthreads();

    const int sr = lane >> 3;  // staging row within 8-row group
    const int sc = lane & 7;   // LDS slot

    // ---- pass 1: row sums of exp(score)*exp(bias) ---------------------------
    float srow[2] = {0.f, 0.f};
    for (int j0 = 0; j0 < SQ; j0 += 64) {
#pragma unroll
        for (int inst = 0; inst < 2; ++inst) {
            int r = w * 16 + inst * 8 + sr;
            gl_lds(&kb[(size_t)(j0 + r) * HD + ((sc ^ (r & 7)) * 8)], &Kl[(w * 16 + inst * 8) * 64]);
        }
        __syncthreads();
#pragma unroll
        for (int ns = 0; ns < 4; ++ns) {
            const int rr = ns * 16 + (lane & 15);
            const int kc = lane >> 4;
            h8 kf0 = *(const h8*)&Kl[rr * 64 + ((kc ^ (rr & 7)) * 8)];
            h8 kf1 = *(const h8*)&Kl[rr * 64 + (((kc + 4) ^ (rr & 7)) * 8)];
#pragma unroll
            for (int isub = 0; isub < 2; ++isub) {
                f4 z = (f4){0.f, 0.f, 0.f, 0.f};
                z = __builtin_amdgcn_mfma_f32_16x16x32_f16(kf0, qf[isub][0], z, 0, 0, 0);
                z = __builtin_amdgcn_mfma_f32_16x16x32_f16(kf1, qf[isub][1], z, 0, 0, 0);
                int u0 =
                    j0 + ns * 16 + ((lane >> 4) << 2) - (w * 32 + isub * 16 + (lane & 15)) + 127;
#pragma unroll
                for (int reg = 0; reg < 4; ++reg)
                    srow[isub] = fmaf(__expf(z[reg]), biasE[u0 + reg], srow[isub]);
            }
        }
        __syncthreads();
    }
    float sinv[2];
#pragma unroll
    for (int isub = 0; isub < 2; ++isub) {
        float s = srow[isub];
        s += __shfl_xor(s, 16);
        s += __shfl_xor(s, 32);
        sinv[isub] = 1.0f / s;
    }

    // ---- pass 2: recompute, nt float4 attw writes, PV -----------------------
    f4 o[4][2];
#pragma unroll
    for (int ns = 0; ns < 4; ++ns)
#pragma unroll
        for (int isub = 0; isub < 2; ++isub) o[ns][isub] = (f4){0.f, 0.f, 0.f, 0.f};
    const size_t awb = (size_t)bh * ((size_t)SQ * SQ);
    char* Pw = Psm + w * 4096;

    for (int j0 = 0; j0 < SQ; j0 += 64) {
#pragma unroll
        for (int inst = 0; inst < 2; ++inst) {
            int r = w * 16 + inst * 8 + sr;
            gl_lds(&kb[(size_t)(j0 + r) * HD + ((sc ^ (r & 7)) * 8)], &Kl[(w * 16 + inst * 8) * 64]);
            gl_lds(&vb[(size_t)r * SQ + j0 + ((sc ^ (r & 7)) * 8)], &Vl[(w * 16 + inst * 8) * 64]);
        }
        __syncthreads();
        f4 a[4][2];
#pragma unroll
        for (int ns = 0; ns < 4; ++ns) {
            const int rr = ns * 16 + (lane & 15);
            const int kc = lane >> 4;
            h8 kf0 = *(const h8*)&Kl[rr * 64 + ((kc ^ (rr & 7)) * 8)];
            h8 kf1 = *(const h8*)&Kl[rr * 64 + (((kc + 4) ^ (rr & 7)) * 8)];
#pragma unroll
            for (int isub = 0; isub < 2; ++isub) {
                f4 z = (f4){0.f, 0.f, 0.f, 0.f};
                z = __builtin_amdgcn_mfma_f32_16x16x32_f16(kf0, qf[isub][0], z, 0, 0, 0);
                z = __builtin_amdgcn_mfma_f32_16x16x32_f16(kf1, qf[isub][1], z, 0, 0, 0);
                a[ns][isub] = z;
            }
        }
#pragma unroll
        for (int ns = 0; ns < 4; ++ns)
#pragma unroll
            for (int isub = 0; isub < 2; ++isub) {
                const int wloc = w * 32 + isub * 16 + (lane & 15);
                const int jbase = ns * 16 + ((lane >> 4) << 2);
                const int u0 = j0 + jbase - wloc + 127;
                f4 p;
#pragma unroll
                for (int reg = 0; reg < 4; ++reg)
                    p[reg] = __expf(a[ns][isub][reg]) * biasE[u0 + reg] * sinv[isub];
                __builtin_nontemporal_store(p, (f4*)&attw[awb + (size_t)(i0 + wloc) * SQ + j0 + jbase]);
                const int iloc = isub * 16 + (lane & 15);
                h4 ph = {(half_t)p[0], (half_t)p[1], (half_t)p[2], (half_t)p[3]};
                *(h4*)&Pw[iloc * 128 + (((jbase >> 3) ^ (iloc & 7)) << 4) + ((jbase & 4) << 1)] = ph;
            }
        h8 pf[2][2];
#pragma unroll
        for (int isub = 0; isub < 2; ++isub) {
            const int iloc = isub * 16 + (lane & 15);
            pf[isub][0] = *(const h8*)&Pw[iloc * 128 + (((lane >> 4) ^ (iloc & 7)) << 4)];
            pf[isub][1] = *(const h8*)&Pw[iloc * 128 + ((((lane >> 4) + 4) ^ (iloc & 7)) << 4)];
        }
#pragma unroll
        for (int ns = 0; ns < 4; ++ns) {
            const int rr = ns * 16 + (lane & 15);
            const int kc = lane >> 4;
            h8 vf0 = *(const h8*)&Vl[rr * 64 + ((kc ^ (rr & 7)) * 8)];
            h8 vf1 = *(const h8*)&Vl[rr * 64 + (((kc + 4) ^ (rr & 7)) * 8)];
#pragma unroll
            for (int isub = 0; isub < 2; ++isub) {
                o[ns][isub] =
                    __builtin_amdgcn_mfma_f32_16x16x32_f16(pf[isub][0], vf0, o[ns][isub], 0, 0, 0);
                o[ns][isub] =
                    __builtin_amdgcn_mfma_f32_16x16x32_f16(pf[isub][1], vf1, o[ns][isub], 0, 0, 0);
            }
        }
        __syncthreads();
    }
#pragma unroll
    for (int ns = 0; ns < 4; ++ns)
#pragma unroll
        for (int isub = 0; isub < 2; ++isub)
#pragma unroll
            for (int reg = 0; reg < 4; ++reg) {
                int row = i0 + w * 32 + isub * 16 + (lane >> 4) * 4 + reg;
                int d = ns * 16 + (lane & 15);
                ctx[((size_t)(b * SQ + row)) * DM + h * HD + d] = (half_t)o[ns][isub][reg];
            }
}

// ---- position_bias fill: pb[h,i,j] = table[bucket(j-i), h] (nt) -------------
__global__ __launch_bounds__(256) void bias_fill(const float* __restrict__ table,
                                                 float* __restrict__ pb) {
    __shared__ float t[512];
    const int tid = threadIdx.x;
    t[tid] = table[tid];
    t[tid + 256] = table[tid + 256];
    __syncthreads();
    const int i = blockIdx.x;
    const int h = blockIdx.y;
    const size_t base = ((size_t)h * SQ + i) * SQ;
#pragma unroll
    for (int half = 0; half < 2; ++half) {
        int j = half * 1024 + tid * 4;
        f4 o;
        o[0] = t[rel_bucket(j + 0 - i) * NH + h];
        o[1] = t[rel_bucket(j + 1 - i) * NH + h];
        o[2] = t[rel_bucket(j + 2 - i) * NH + h];
        o[3] = t[rel_bucket(j + 3 - i) * NH + h];
        __builtin_nontemporal_store(o, (f4*)&pb[base + j]);
    }
}

extern "C" void kernel_launch(void* const* d_in, const int* in_sizes, int n_in, void* d_out,
                              int out_size, void* d_ws, size_t ws_size, hipStream_t stream) {
    const float* X = (const float*)d_in[0];
    const float* Wq = (const float*)d_in[1];
    const float* Wk = (const float*)d_in[2];
    const float* Wv = (const float*)d_in[3];
    const float* Wo = (const float*)d_in[4];
    const float* tbl = (const float*)d_in[5];

    float* out = (float*)d_out;
    float* attn_out = out;                    // 8,388,608 f32
    float* pb = out + (size_t)NB * SQ * DM;   // 67,108,864 f32
    float* attw = pb + (size_t)NH * SQ * SQ;  // 268,435,456 f32

    // f16 scratch: prefer d_ws; fall back to pb region (bias_fill overwrites LAST)
    const size_t need_bytes = 109051904;  // 54,525,952 halfs
    half_t* hb = (ws_size >= need_bytes) ? (half_t*)d_ws : (half_t*)pb;
    half_t* Xh = hb;
    half_t* qh = hb + 8388608;
    half_t* kh = hb + 16777216;
    half_t* vh = hb + 25165824;
    half_t* vTh = hb + 33554432;
    half_t* ctxh = hb + 41943040;
    half_t* Wqt = hb + 50331648;
    half_t* Wkt = hb + 51380224;
    half_t* Wvt = hb + 52428800;
    half_t* Wot = hb + 53477376;

    dim3 blk(256);
    prep<<<dim3(5120), blk, 0, stream>>>(X, Wq, Wk, Wv, Wo, Xh, Wqt, Wkt, Wvt, Wot);
    mm_qkv<<<dim3(8, 64, 3), blk, 0, stream>>>(Xh, Wqt, Wkt, Wvt, qh, kh, vh);
    transpose_v<<<dim3(32, 64), blk, 0, stream>>>(vh, vTh);
    fused_attn<<<dim3(1024), blk, 0, stream>>>(qh, kh, vTh, tbl, attw, ctxh);
    mm_wo<<<dim3(8, 64), blk, 0, stream>>>(ctxh, Wot, attn_out);
    bias_fill<<<dim3(SQ, NH), blk, 0, stream>>>(tbl, pb);
}